// Round 7
// baseline (1954.968 us; speedup 1.0000x reference)
//
#include <hip/hip_runtime.h>
#include <hip/hip_bf16.h>
#include <math.h>

#define B_SZ    64
#define SEQ     2048
#define DMODEL  128
#define DINNER  256
#define DSTATE  16
#define NLAYERS 5
#define NSEG    32
#define LSEG    64          /* SEQ/NSEG */

typedef unsigned short u16;
typedef __attribute__((ext_vector_type(8))) short bf16x8;
typedef __attribute__((ext_vector_type(4))) float f32x4;

static __device__ __forceinline__ float bf2f(u16 u){
  union { unsigned u; float f; } a; a.u = ((unsigned)u) << 16; return a.f;
}
static __device__ __forceinline__ u16 f2bf(float f){
  union { float f; unsigned u; } a; a.f = f;
  unsigned r = a.u + 0x7fffu + ((a.u >> 16) & 1u);
  return (u16)(r >> 16);
}
static __device__ __forceinline__ float sigm(float x){ return 1.f/(1.f+__expf(-x)); }
static __device__ __forceinline__ float siluf(float x){ return x/(1.f+__expf(-x)); }

#define MFMA16(a,b,c) __builtin_amdgcn_mfma_f32_16x16x32_bf16((a),(b),(c),0,0,0)

/* ---------------- weight prep: transpose to [N][K] + bf16 ---------------- */
__global__ __launch_bounds__(256) void prep_kernel(
    const float* __restrict__ in_w, const float* __restrict__ xp_w,
    const float* __restrict__ dt_w, const float* __restrict__ out_w,
    u16* __restrict__ WT1, u16* __restrict__ WT2, u16* __restrict__ WT3){
  int idx = blockIdx.x*256 + threadIdx.x;
  const int n1 = NLAYERS*512*128, n2 = NLAYERS*288*256, n3 = NLAYERS*128*256;
  if (idx < n1){
    int l = idx/(512*128), r = idx%(512*128), n = r/128, k = r%128;
    WT1[idx] = f2bf(in_w[((size_t)l*128 + k)*512 + n]);
  } else if (idx < n1+n2){
    int t = idx-n1; int l=t/(288*256), r=t%(288*256), n=r/256, k=r%256;
    float v = (n<32) ? xp_w[((size_t)l*256+k)*32 + n]
                     : dt_w[((size_t)l*256+k)*256 + (n-32)];
    WT2[t] = f2bf(v);
  } else if (idx < n1+n2+n3){
    int t = idx-n1-n2; int l=t/(128*256), r=t%(128*256), n=r/256, k=r%256;
    WT3[t] = f2bf(out_w[((size_t)l*256+k)*128 + n]);
  }
}

/* ------- embedding: h = x @ emb_w + emb_b, write tiled bf16 Hb ----------- */
__global__ __launch_bounds__(256) void emb_kernel(
    const float* __restrict__ x, const float* __restrict__ ew,
    const float* __restrict__ eb, u16* __restrict__ Hb, size_t cs){
  int idx = blockIdx.x*256 + threadIdx.x;
  int m = idx >> 7, d = idx & 127;
  float s = eb[d];
  #pragma unroll
  for (int k=0;k<16;++k) s += x[(size_t)m*16+k]*ew[k*128+d];
  Hb[(size_t)(d>>4)*cs + (size_t)m*16 + (d&15)] = f2bf(s);
}

/* -- GEMM1: R=4 rows/wave, half-split, prefetch; tiled loads/stores ------- */
__global__ __launch_bounds__(256) void gemm1_kernel(
    const u16* __restrict__ Hb, const u16* __restrict__ WT,
    const float* __restrict__ bias, u16* __restrict__ U, u16* __restrict__ ZS,
    size_t cs){
  const int lane = threadIdx.x & 63, wave = threadIdx.x >> 6;
  const int half = blockIdx.x & 1;
  const int m0 = (blockIdx.x >> 1)*256 + wave*64;
  const int lr = lane & 15, kg = lane >> 4;
  bf16x8 hfrag[4][4];
  #pragma unroll
  for (int g=0; g<4; ++g)
    #pragma unroll
    for (int f=0; f<4; ++f)
      hfrag[g][f] = *(const bf16x8*)(Hb + (size_t)((kg>>1)+2*f)*cs
                                     + (size_t)(m0+g*16+lr)*16 + (kg&1)*8);
  u16* const dst = half ? ZS : U;
  const u16* wrow = WT + (size_t)(half*256+lr)*128 + kg*8;
  bf16x8 wv[4];
  #pragma unroll
  for (int f=0; f<4; ++f) wv[f] = *(const bf16x8*)(wrow + f*32);
  #pragma unroll
  for (int nn=0; nn<16; ++nn){
    bf16x8 wn[4];
    if (nn < 15){
      const u16* wr2 = wrow + (size_t)(nn+1)*16*128;
      #pragma unroll
      for (int f=0; f<4; ++f) wn[f] = *(const bf16x8*)(wr2 + f*32);
    }
    f32x4 acc[4];
    #pragma unroll
    for (int g=0; g<4; ++g){
      acc[g] = (f32x4){0.f,0.f,0.f,0.f};
      #pragma unroll
      for (int f=0; f<4; ++f) acc[g] = MFMA16(wv[f], hfrag[g][f], acc[g]);
    }
    float4 bs4 = *(const float4*)(bias + half*256 + nn*16 + kg*4);
    #pragma unroll
    for (int g=0; g<4; ++g){
      ushort4 uv;
      uv.x = f2bf(siluf(acc[g][0]+bs4.x));
      uv.y = f2bf(siluf(acc[g][1]+bs4.y));
      uv.z = f2bf(siluf(acc[g][2]+bs4.z));
      uv.w = f2bf(siluf(acc[g][3]+bs4.w));
      *(ushort4*)(dst + (size_t)nn*cs + (size_t)(m0+g*16+lr)*16 + kg*4) = uv;
    }
    #pragma unroll
    for (int f=0; f<4; ++f) wv[f] = wn[f];
  }
}

/* -- GEMM2: R=2 rows/wave, prefetch; tiled U in, tiled BC/DT out ---------- */
__global__ __launch_bounds__(256) void gemm2_kernel(
    const u16* __restrict__ Uin, const u16* __restrict__ WT,
    const float* __restrict__ xpb, const float* __restrict__ dtb,
    u16* __restrict__ BC, u16* __restrict__ DT, size_t cs){
  const int lane = threadIdx.x & 63, wave = threadIdx.x >> 6;
  const int m0 = blockIdx.x*128 + wave*32;
  const int lr = lane & 15, kg = lane >> 6 ? 0 : (lane >> 4);   /* kg = lane>>4 */
  const int kgr = lane >> 4;
  bf16x8 hfrag[2][8];
  #pragma unroll
  for (int g=0; g<2; ++g)
    #pragma unroll
    for (int f=0; f<8; ++f)
      hfrag[g][f] = *(const bf16x8*)(Uin + (size_t)((kgr>>1)+2*f)*cs
                                     + (size_t)(m0+g*16+lr)*16 + (kgr&1)*8);
  const u16* wrow = WT + (size_t)lr*256 + kgr*8;
  bf16x8 wv[8];
  #pragma unroll
  for (int f=0; f<8; ++f) wv[f] = *(const bf16x8*)(wrow + f*32);
  #pragma unroll
  for (int nn=0; nn<18; ++nn){
    bf16x8 wn[8];
    if (nn < 17){
      const u16* wr2 = wrow + (size_t)(nn+1)*16*256;
      #pragma unroll
      for (int f=0; f<8; ++f) wn[f] = *(const bf16x8*)(wr2 + f*32);
    }
    f32x4 acc[2];
    #pragma unroll
    for (int g=0; g<2; ++g){
      acc[g] = (f32x4){0.f,0.f,0.f,0.f};
      #pragma unroll
      for (int f=0; f<8; ++f) acc[g] = MFMA16(wv[f], hfrag[g][f], acc[g]);
    }
    const int col0 = nn*16 + kgr*4;
    if (col0 < 32){
      float4 bs4 = *(const float4*)(xpb + col0);
      #pragma unroll
      for (int g=0; g<2; ++g){
        ushort4 uv;
        uv.x = f2bf(acc[g][0]+bs4.x); uv.y = f2bf(acc[g][1]+bs4.y);
        uv.z = f2bf(acc[g][2]+bs4.z); uv.w = f2bf(acc[g][3]+bs4.w);
        *(ushort4*)(BC + (size_t)nn*cs + (size_t)(m0+g*16+lr)*16 + kgr*4) = uv;
      }
    } else {
      float4 bs4 = *(const float4*)(dtb + (col0-32));
      #pragma unroll
      for (int g=0; g<2; ++g){
        float v0=acc[g][0]+bs4.x, v1=acc[g][1]+bs4.y;
        float v2=acc[g][2]+bs4.z, v3=acc[g][3]+bs4.w;
        ushort4 uv;
        uv.x = f2bf(fmaxf(v0,0.f) + __logf(1.f + __expf(-fabsf(v0))));
        uv.y = f2bf(fmaxf(v1,0.f) + __logf(1.f + __expf(-fabsf(v1))));
        uv.z = f2bf(fmaxf(v2,0.f) + __logf(1.f + __expf(-fabsf(v2))));
        uv.w = f2bf(fmaxf(v3,0.f) + __logf(1.f + __expf(-fabsf(v3))));
        *(ushort4*)(DT + (size_t)(nn-2)*cs + (size_t)(m0+g*16+lr)*16 + kgr*4) = uv;
      }
    }
    #pragma unroll
    for (int f=0; f<8; ++f) wv[f] = wn[f];
  }
}

/* depth-4 power tree: pw[i] = r^(i+1), i=0..15 */
static __device__ __forceinline__ void powtree(float r, float* pw){
  float p2=r*r, p3=p2*r, p4=p2*p2;
  float p5=p4*r, p6=p4*p2, p7=p4*p3, p8=p4*p4;
  pw[0]=r;  pw[1]=p2; pw[2]=p3; pw[3]=p4;
  pw[4]=p5; pw[5]=p6; pw[6]=p7; pw[7]=p8;
  pw[8]=p8*r;  pw[9]=p8*p2;  pw[10]=p8*p3;  pw[11]=p8*p4;
  pw[12]=p8*p5; pw[13]=p8*p6; pw[14]=p8*p7; pw[15]=p8*p8;
}

/* ---------- scan pass 1: local scan, end-state + sum(dt) ----------------- */
__global__ __launch_bounds__(256) void scan_p1(
    const u16* __restrict__ U, const u16* __restrict__ DT,
    const u16* __restrict__ BC, const float* __restrict__ Alog,
    u16* __restrict__ SGH, float* __restrict__ SDT, size_t cs){
  const int seg = blockIdx.x % NSEG;
  const int b   = blockIdx.x / NSEG;
  const int c   = threadIdx.x;
  const size_t coff = (size_t)(c>>4)*cs + (c&15);
  float a2[16]; bool geo = true;
  #pragma unroll
  for (int i=0;i<16;++i){
    float A = -__expf(Alog[c*16+i]);
    a2[i] = A * 1.44269504f;
    if (fabsf(A + (float)(i+1)) > 1e-3f) geo = false;
  }
  float h[16];
  #pragma unroll
  for (int i=0;i<16;++i) h[i]=0.f;
  float sdt = 0.f;
  const size_t mbase = (size_t)b*SEQ + (size_t)seg*LSEG;
  if (geo){
    for (int t=0;t<LSEG;++t){
      const size_t m = mbase + t;
      float u  = bf2f(U [coff + m*16]);
      float dt = bf2f(DT[coff + m*16]);
      bf16x8 b0 = *(const bf16x8*)(BC + m*16);
      bf16x8 b1 = *(const bf16x8*)(BC + m*16 + 8);
      float du = dt*u; sdt += dt;
      float r = exp2f(-1.44269504f*dt);
      float pw[16]; powtree(r, pw);
      #pragma unroll
      for (int i=0;i<8;++i)  h[i]   = h[i]  *pw[i]   + du*bf2f((u16)b0[i]);
      #pragma unroll
      for (int i=8;i<16;++i) h[i]   = h[i]  *pw[i]   + du*bf2f((u16)b1[i-8]);
    }
  } else {
    for (int t=0;t<LSEG;++t){
      const size_t m = mbase + t;
      float u  = bf2f(U [coff + m*16]);
      float dt = bf2f(DT[coff + m*16]);
      bf16x8 b0 = *(const bf16x8*)(BC + m*16);
      bf16x8 b1 = *(const bf16x8*)(BC + m*16 + 8);
      float du = dt*u; sdt += dt;
      #pragma unroll
      for (int i=0;i<16;++i){
        float Bv = (i<8) ? bf2f((u16)b0[i]) : bf2f((u16)b1[i-8]);
        h[i] = h[i]*exp2f(dt*a2[i]) + du*Bv;
      }
    }
  }
  const size_t kb = ((size_t)b*NSEG+seg);
  #pragma unroll
  for (int i=0;i<16;++i) SGH[(kb*16+i)*256 + c] = f2bf(h[i]);
  SDT[kb*256 + c] = sdt;
}

/* ---------- scan pass 2: combine; SGH <- h0 per segment ------------------ */
__global__ __launch_bounds__(256) void scan_p2(
    u16* __restrict__ SGH, const float* __restrict__ SDT,
    const float* __restrict__ Alog){
  const int i = blockIdx.x & 15, b = blockIdx.x >> 4, c = threadIdx.x;
  const float a2 = -__expf(Alog[c*16+i]) * 1.44269504f;
  float h = 0.f;
  for (int s=0;s<NSEG;++s){
    const size_t kb = ((size_t)b*NSEG+s);
    float sdt = SDT[kb*256 + c];
    size_t k = (kb*16+i)*256 + c;
    float hl = bf2f(SGH[k]);
    SGH[k] = f2bf(h);
    h = h*exp2f(sdt*a2) + hl;
  }
}

/* ---- fused scan pass3 -> ys(LDS) -> GEMM3 + residual + LayerNorm -------- */
__global__ __launch_bounds__(256) void scan3ln_kernel(
    const u16* __restrict__ U, const u16* __restrict__ DT,
    const u16* __restrict__ BC, const u16* __restrict__ ZS,
    const float* __restrict__ Alog, const float* __restrict__ Dp,
    const u16* __restrict__ SGH, const u16* __restrict__ WT,
    const float* __restrict__ ob, const float* __restrict__ gv,
    const float* __restrict__ bbv, u16* __restrict__ Hb, size_t cs){
  __shared__ u16 ysl[LSEG*264];                /* 264 = 256 + 8 pad */
  const int seg = blockIdx.x % NSEG;
  const int b   = blockIdx.x / NSEG;
  /* ---- phase 1: segment scan, thread = channel c ---- */
  {
    const int c = threadIdx.x;
    const size_t coff = (size_t)(c>>4)*cs + (c&15);
    float a2[16]; bool geo = true;
    #pragma unroll
    for (int i=0;i<16;++i){
      float A = -__expf(Alog[c*16+i]);
      a2[i] = A * 1.44269504f;
      if (fabsf(A + (float)(i+1)) > 1e-3f) geo = false;
    }
    const float Dv = Dp[c];
    const size_t kb = ((size_t)b*NSEG+seg);
    float h[16];
    #pragma unroll
    for (int i=0;i<16;++i) h[i] = bf2f(SGH[(kb*16+i)*256 + c]);
    const size_t mbase = (size_t)b*SEQ + (size_t)seg*LSEG;
    if (geo){
      for (int t=0;t<LSEG;++t){
        const size_t m = mbase + t;
        float u  = bf2f(U [coff + m*16]);
        float dt = bf2f(DT[coff + m*16]);
        float zs = bf2f(ZS[coff + m*16]);
        bf16x8 b0 = *(const bf16x8*)(BC + m*16);
        bf16x8 b1 = *(const bf16x8*)(BC + m*16 + 8);
        bf16x8 c0 = *(const bf16x8*)(BC + cs + m*16);
        bf16x8 c1 = *(const bf16x8*)(BC + cs + m*16 + 8);
        float du = dt*u;
        float r = exp2f(-1.44269504f*dt);
        float pw[16]; powtree(r, pw);
        float s0=0.f, s1=0.f;
        #pragma unroll
        for (int i=0;i<8;++i){
          h[i] = h[i]*pw[i] + du*bf2f((u16)b0[i]);
          s0 += h[i]*bf2f((u16)c0[i]);
        }
        #pragma unroll
        for (int i=8;i<16;++i){
          h[i] = h[i]*pw[i] + du*bf2f((u16)b1[i-8]);
          s1 += h[i]*bf2f((u16)c1[i-8]);
        }
        float y = s0 + s1 + Dv*u;
        ysl[t*264 + c] = f2bf(y*zs);
      }
    } else {
      for (int t=0;t<LSEG;++t){
        const size_t m = mbase + t;
        float u  = bf2f(U [coff + m*16]);
        float dt = bf2f(DT[coff + m*16]);
        float zs = bf2f(ZS[coff + m*16]);
        bf16x8 b0 = *(const bf16x8*)(BC + m*16);
        bf16x8 b1 = *(const bf16x8*)(BC + m*16 + 8);
        bf16x8 c0 = *(const bf16x8*)(BC + cs + m*16);
        bf16x8 c1 = *(const bf16x8*)(BC + cs + m*16 + 8);
        float du = dt*u;
        float s0=0.f, s1=0.f;
        #pragma unroll
        for (int i=0;i<8;++i){
          h[i] = h[i]*exp2f(dt*a2[i]) + du*bf2f((u16)b0[i]);
          s0 += h[i]*bf2f((u16)c0[i]);
        }
        #pragma unroll
        for (int i=8;i<16;++i){
          h[i] = h[i]*exp2f(dt*a2[i]) + du*bf2f((u16)b1[i-8]);
          s1 += h[i]*bf2f((u16)c1[i-8]);
        }
        float y = s0 + s1 + Dv*u;
        ysl[t*264 + c] = f2bf(y*zs);
      }
    }
  }
  __syncthreads();
  /* ---- phase 2: GEMM3 (N=128,K=256) + residual + LN, wave = 16 rows ---- */
  {
    const int lane = threadIdx.x & 63, wave = threadIdx.x >> 6;
    const int lr = lane & 15, kg = lane >> 4;
    const int lw = wave*16 + lr;                       /* local row 0..63 */
    const size_t m = (size_t)b*SEQ + (size_t)seg*LSEG + lw;
    bf16x8 hfrag[8];
    #pragma unroll
    for (int f=0; f<8; ++f)
      hfrag[f] = *(const bf16x8*)(&ysl[lw*264 + kg*8 + f*32]);
    const u16* wrow = WT + (size_t)lr*256 + kg*8;
    bf16x8 wv[8];
    #pragma unroll
    for (int f=0; f<8; ++f) wv[f] = *(const bf16x8*)(wrow + f*32);
    ushort4 xvp[8];
    float s = 0.f, q = 0.f;
    #pragma unroll
    for (int n=0; n<8; ++n){
      bf16x8 wn[8];
      if (n < 7){
        const u16* wr2 = wrow + (size_t)(n+1)*16*256;
        #pragma unroll
        for (int f=0; f<8; ++f) wn[f] = *(const bf16x8*)(wr2 + f*32);
      }
      f32x4 acc = {0.f,0.f,0.f,0.f};
      #pragma unroll
      for (int f=0; f<8; ++f) acc = MFMA16(wv[f], hfrag[f], acc);
      const int col0 = n*16 + kg*4;
      float4 bs4 = *(const float4*)(ob + col0);
      ushort4 rs = *(const ushort4*)(Hb + (size_t)n*cs + m*16 + kg*4);
      float x0 = acc[0] + bs4.x + bf2f(rs.x);
      float x1 = acc[1] + bs4.y + bf2f(rs.y);
      float x2 = acc[2] + bs4.z + bf2f(rs.z);
      float x3 = acc[3] + bs4.w + bf2f(rs.w);
      s += (x0+x1)+(x2+x3);
      q += (x0*x0+x1*x1)+(x2*x2+x3*x3);
      ushort4 pv; pv.x=f2bf(x0); pv.y=f2bf(x1); pv.z=f2bf(x2); pv.w=f2bf(x3);
      xvp[n] = pv;
      #pragma unroll
      for (int f=0; f<8; ++f) wv[f] = wn[f];
    }
    s += __shfl_xor(s,16); q += __shfl_xor(q,16);
    s += __shfl_xor(s,32); q += __shfl_xor(q,32);
    float mu  = s * 0.0078125f;
    float var = q * 0.0078125f - mu*mu;
    float inv = rsqrtf(var + 1e-5f);
    #pragma unroll
    for (int n=0;n<8;++n){
      const int col0 = n*16 + kg*4;
      float4 g4 = *(const float4*)(gv  + col0);
      float4 b4 = *(const float4*)(bbv + col0);
      ushort4 pv = xvp[n];
      ushort4 uv;
      uv.x = f2bf((bf2f(pv.x)-mu)*inv*g4.x + b4.x);
      uv.y = f2bf((bf2f(pv.y)-mu)*inv*g4.y + b4.y);
      uv.z = f2bf((bf2f(pv.z)-mu)*inv*g4.z + b4.z);
      uv.w = f2bf((bf2f(pv.w)-mu)*inv*g4.w + b4.w);
      *(ushort4*)(Hb + (size_t)n*cs + m*16 + kg*4) = uv;
    }
  }
}

/* ---------------- two-stage mean over SEQ (tiled bf16 Hb) ---------------- */
__global__ __launch_bounds__(128) void pool1_kernel(
    const u16* __restrict__ Hb, float* __restrict__ PP, size_t cs){
  const int blk = blockIdx.x;
  const int tc = blk & 15, b = blk >> 4;
  const int d = threadIdx.x;
  const size_t coff = (size_t)(d>>4)*cs + (d&15);
  float s = 0.f;
  const size_t base = ((size_t)b*SEQ + tc*128);
  for (int t=0;t<128;++t) s += bf2f(Hb[coff + (base+t)*16]);
  PP[((size_t)b*16 + tc)*128 + d] = s;
}
__global__ __launch_bounds__(128) void pool2_kernel(
    const float* __restrict__ PP, float* __restrict__ P){
  const int b = blockIdx.x, d = threadIdx.x;
  float s = 0.f;
  #pragma unroll
  for (int tc=0;tc<16;++tc) s += PP[((size_t)b*16+tc)*128 + d];
  P[b*128 + d] = s * (1.f/SEQ);
}

/* ------------- head MLP + final formula (block per batch row) ----------- */
__global__ __launch_bounds__(64) void head_kernel(
    const float* __restrict__ P, const float* __restrict__ o1w,
    const float* __restrict__ o1b, const float* __restrict__ o2w,
    const float* __restrict__ o2b, const float* __restrict__ origins,
    float* __restrict__ out){
  const int b = blockIdx.x;
  const int j = threadIdx.x;
  float hv = o1b[j];
  #pragma unroll 4
  for (int d=0; d<128; ++d) hv += P[b*128+d]*o1w[d*64+j];
  hv = fmaxf(hv, 0.f);
  float p0 = hv*o2w[j*3+0], p1 = hv*o2w[j*3+1], p2 = hv*o2w[j*3+2];
  #pragma unroll
  for (int o=1;o<64;o<<=1){
    p0 += __shfl_xor(p0,o); p1 += __shfl_xor(p1,o); p2 += __shfl_xor(p2,o);
  }
  if (j == 0){
    float a = 2.f*sigm(p0 + o2b[0]);
    float bb = 2.f*sigm(p1 + o2b[1]);
    float c = 2.f*sigm(p2 + o2b[2]);
    const float* l1 = origins + ((size_t)b*SEQ + (SEQ-1))*16;
    const float* l2 = origins + ((size_t)b*SEQ + (SEQ-2))*16;
    float price=l1[0], ry_n=l1[1], ry_b=l2[1], gy_n=l1[2], gy_b=l2[2], ny_n=l1[3], ny_b=l2[3];
    out[b] = price*a*ry_n/ry_b*2.f*(bb*sigm(gy_n-gy_b) + c*sigm(ny_n-ny_b));
  }
}

extern "C" void kernel_launch(void* const* d_in, const int* in_sizes, int n_in,
                              void* d_out, int out_size, void* d_ws, size_t ws_size,
                              hipStream_t stream){
  const float* origins = (const float*)d_in[0];
  const float* x      = (const float*)d_in[1];
  const float* emb_w  = (const float*)d_in[2];
  const float* emb_b  = (const float*)d_in[3];
  const float* in_w   = (const float*)d_in[4];
  const float* in_b   = (const float*)d_in[5];
  const float* xp_w   = (const float*)d_in[6];
  const float* xp_b   = (const float*)d_in[7];
  const float* dt_w   = (const float*)d_in[8];
  const float* dt_b   = (const float*)d_in[9];
  const float* out_w  = (const float*)d_in[10];
  const float* out_b  = (const float*)d_in[11];
  const float* A_log  = (const float*)d_in[12];
  const float* Dp     = (const float*)d_in[13];
  const float* ln_g   = (const float*)d_in[14];
  const float* ln_b   = (const float*)d_in[15];
  const float* o1_w   = (const float*)d_in[16];
  const float* o1_b   = (const float*)d_in[17];
  const float* o2_w   = (const float*)d_in[18];
  const float* o2_b   = (const float*)d_in[19];
  float* outp = (float*)d_out;

  auto al = [](size_t b)->size_t{ return (b + 255) & ~(size_t)255; };
  const size_t wt1_b = al((size_t)NLAYERS*512*128*2);
  const size_t wt2_b = al((size_t)NLAYERS*288*256*2);
  const size_t wt3_b = al((size_t)NLAYERS*128*256*2);
  const size_t po_b  = al((size_t)B_SZ*128*4);
  const size_t pp_b  = al((size_t)B_SZ*16*128*4);
  const size_t fixed = wt1_b + wt2_b + wt3_b + po_b + pp_b;

  int CB = 0;
  static const int cbc[7] = {64,32,16,8,4,2,1};
  size_t hb_b=0, u_b=0, bc_b=0, sgh_b=0, sdt_b=0;
  for (int i=0;i<7;++i){
    int cb = cbc[i];
    size_t csz = (size_t)cb*SEQ*16;               /* chunk stride, elements */
    size_t hbb = al(8*csz*2);
    size_t uu  = al(16*csz*2);
    size_t bb  = al(2*csz*2);
    size_t sgh = al((size_t)cb*NSEG*DSTATE*DINNER*2);
    size_t sdt = al((size_t)cb*NSEG*DINNER*4);
    if (fixed + hbb + 3*uu + bb + sgh + sdt <= ws_size){
      CB=cb; hb_b=hbb; u_b=uu; bc_b=bb; sgh_b=sgh; sdt_b=sdt; break;
    }
  }
  if (!CB) return;

  char* ws = (char*)d_ws;
  size_t off = 0;
  auto take = [&](size_t bytes)->char*{ char* p = ws + off; off += bytes; return p; };
  u16*   WT1 = (u16*)take(wt1_b);
  u16*   WT2 = (u16*)take(wt2_b);
  u16*   WT3 = (u16*)take(wt3_b);
  float* PO  = (float*)take(po_b);
  float* PP  = (float*)take(pp_b);
  u16*   Hb  = (u16*)take(hb_b);
  u16*   U   = (u16*)take(u_b);
  u16*   ZS  = (u16*)take(u_b);
  u16*   DT  = (u16*)take(u_b);
  u16*   BC  = (u16*)take(bc_b);
  u16*   SGH = (u16*)take(sgh_b);
  float* SDT = (float*)take(sdt_b);

  prep_kernel<<<3360, 256, 0, stream>>>(in_w, xp_w, dt_w, out_w, WT1, WT2, WT3);

  const int NC = B_SZ / CB;
  const int Mc = CB * SEQ;
  const size_t cs = (size_t)Mc*16;
  for (int ci=0; ci<NC; ++ci){
    const int b0 = ci * CB;
    const size_t R0 = (size_t)b0 * SEQ;
    emb_kernel<<<(Mc*DMODEL)/256, 256, 0, stream>>>(x + R0*16, emb_w, emb_b, Hb, cs);
    for (int l=0;l<NLAYERS;++l){
      const float* Al = A_log + (size_t)l*DINNER*DSTATE;
      gemm1_kernel<<<(Mc/256)*2, 256, 0, stream>>>(Hb, WT1 + (size_t)l*512*128,
                                                   in_b + l*512, U, ZS, cs);
      gemm2_kernel<<<Mc/128, 256, 0, stream>>>(U, WT2 + (size_t)l*288*256,
                                               xp_b + l*32, dt_b + l*256, BC, DT, cs);
      scan_p1<<<CB*NSEG, 256, 0, stream>>>(U, DT, BC, Al, SGH, SDT, cs);
      scan_p2<<<CB*16, 256, 0, stream>>>(SGH, SDT, Al);
      scan3ln_kernel<<<CB*NSEG, 256, 0, stream>>>(U, DT, BC, ZS, Al, Dp + l*DINNER,
                                                  SGH, WT3 + (size_t)l*128*256,
                                                  out_b + l*128, ln_g + l*128,
                                                  ln_b + l*128, Hb, cs);
    }
    pool1_kernel<<<CB*16, 128, 0, stream>>>(Hb, PP, cs);
    pool2_kernel<<<CB, 128, 0, stream>>>(PP, PO + (size_t)b0*128);
  }
  head_kernel<<<B_SZ, 64, 0, stream>>>(PO, o1_w, o1_b, o2_w, o2_b, origins, outp);
}

// Round 8
// 1768.952 us; speedup vs baseline: 1.1052x; 1.1052x over previous
//
#include <hip/hip_runtime.h>
#include <hip/hip_bf16.h>
#include <math.h>

#define B_SZ    64
#define SEQ     2048
#define DMODEL  128
#define DINNER  256
#define DSTATE  16
#define NLAYERS 5
#define NSEG    32
#define LSEG    64          /* SEQ/NSEG */

typedef unsigned short u16;
typedef __attribute__((ext_vector_type(8))) short bf16x8;
typedef __attribute__((ext_vector_type(4))) float f32x4;

static __device__ __forceinline__ float bf2f(u16 u){
  union { unsigned u; float f; } a; a.u = ((unsigned)u) << 16; return a.f;
}
static __device__ __forceinline__ u16 f2bf(float f){
  union { float f; unsigned u; } a; a.f = f;
  unsigned r = a.u + 0x7fffu + ((a.u >> 16) & 1u);
  return (u16)(r >> 16);
}
static __device__ __forceinline__ float sigm(float x){ return 1.f/(1.f+__expf(-x)); }
static __device__ __forceinline__ float siluf(float x){ return x/(1.f+__expf(-x)); }

#define MFMA16(a,b,c) __builtin_amdgcn_mfma_f32_16x16x32_bf16((a),(b),(c),0,0,0)

/* ---------------- weight prep: transpose to [N][K] + bf16 ---------------- */
__global__ __launch_bounds__(256) void prep_kernel(
    const float* __restrict__ in_w, const float* __restrict__ xp_w,
    const float* __restrict__ dt_w, const float* __restrict__ out_w,
    u16* __restrict__ WT1, u16* __restrict__ WT2, u16* __restrict__ WT3){
  int idx = blockIdx.x*256 + threadIdx.x;
  const int n1 = NLAYERS*512*128, n2 = NLAYERS*288*256, n3 = NLAYERS*128*256;
  if (idx < n1){
    int l = idx/(512*128), r = idx%(512*128), n = r/128, k = r%128;
    WT1[idx] = f2bf(in_w[((size_t)l*128 + k)*512 + n]);
  } else if (idx < n1+n2){
    int t = idx-n1; int l=t/(288*256), r=t%(288*256), n=r/256, k=r%256;
    float v = (n<32) ? xp_w[((size_t)l*256+k)*32 + n]
                     : dt_w[((size_t)l*256+k)*256 + (n-32)];
    WT2[t] = f2bf(v);
  } else if (idx < n1+n2+n3){
    int t = idx-n1-n2; int l=t/(128*256), r=t%(128*256), n=r/256, k=r%256;
    WT3[t] = f2bf(out_w[((size_t)l*256+k)*128 + n]);
  }
}

/* ------- embedding: h = x @ emb_w + emb_b, write tiled bf16 Hb ----------- */
__global__ __launch_bounds__(256) void emb_kernel(
    const float* __restrict__ x, const float* __restrict__ ew,
    const float* __restrict__ eb, u16* __restrict__ Hb, size_t cs){
  int idx = blockIdx.x*256 + threadIdx.x;
  int m = idx >> 7, d = idx & 127;
  float s = eb[d];
  #pragma unroll
  for (int k=0;k<16;++k) s += x[(size_t)m*16+k]*ew[k*128+d];
  Hb[(size_t)(d>>4)*cs + (size_t)m*16 + (d&15)] = f2bf(s);
}

/* -- GEMM1: R=4 rows/wave, half-split, prefetch; tiled loads/stores ------- */
__global__ __launch_bounds__(256) void gemm1_kernel(
    const u16* __restrict__ Hb, const u16* __restrict__ WT,
    const float* __restrict__ bias, u16* __restrict__ U, u16* __restrict__ ZS,
    size_t cs){
  const int lane = threadIdx.x & 63, wave = threadIdx.x >> 6;
  const int half = blockIdx.x & 1;
  const int m0 = (blockIdx.x >> 1)*256 + wave*64;
  const int lr = lane & 15, kg = lane >> 4;
  bf16x8 hfrag[4][4];
  #pragma unroll
  for (int g=0; g<4; ++g)
    #pragma unroll
    for (int f=0; f<4; ++f)
      hfrag[g][f] = *(const bf16x8*)(Hb + (size_t)((kg>>1)+2*f)*cs
                                     + (size_t)(m0+g*16+lr)*16 + (kg&1)*8);
  u16* const dst = half ? ZS : U;
  const u16* wrow = WT + (size_t)(half*256+lr)*128 + kg*8;
  bf16x8 wv[4];
  #pragma unroll
  for (int f=0; f<4; ++f) wv[f] = *(const bf16x8*)(wrow + f*32);
  #pragma unroll
  for (int nn=0; nn<16; ++nn){
    bf16x8 wn[4];
    if (nn < 15){
      const u16* wr2 = wrow + (size_t)(nn+1)*16*128;
      #pragma unroll
      for (int f=0; f<4; ++f) wn[f] = *(const bf16x8*)(wr2 + f*32);
    }
    f32x4 acc[4];
    #pragma unroll
    for (int g=0; g<4; ++g){
      acc[g] = (f32x4){0.f,0.f,0.f,0.f};
      #pragma unroll
      for (int f=0; f<4; ++f) acc[g] = MFMA16(wv[f], hfrag[g][f], acc[g]);
    }
    float4 bs4 = *(const float4*)(bias + half*256 + nn*16 + kg*4);
    #pragma unroll
    for (int g=0; g<4; ++g){
      ushort4 uv;
      uv.x = f2bf(siluf(acc[g][0]+bs4.x));
      uv.y = f2bf(siluf(acc[g][1]+bs4.y));
      uv.z = f2bf(siluf(acc[g][2]+bs4.z));
      uv.w = f2bf(siluf(acc[g][3]+bs4.w));
      *(ushort4*)(dst + (size_t)nn*cs + (size_t)(m0+g*16+lr)*16 + kg*4) = uv;
    }
    #pragma unroll
    for (int f=0; f<4; ++f) wv[f] = wn[f];
  }
}

/* -- GEMM2: R=2 rows/wave, prefetch; tiled U in, tiled BC/DT out ---------- */
__global__ __launch_bounds__(256) void gemm2_kernel(
    const u16* __restrict__ Uin, const u16* __restrict__ WT,
    const float* __restrict__ xpb, const float* __restrict__ dtb,
    u16* __restrict__ BC, u16* __restrict__ DT, size_t cs){
  const int lane = threadIdx.x & 63, wave = threadIdx.x >> 6;
  const int m0 = blockIdx.x*128 + wave*32;
  const int lr = lane & 15, kg = lane >> 4;
  bf16x8 hfrag[2][8];
  #pragma unroll
  for (int g=0; g<2; ++g)
    #pragma unroll
    for (int f=0; f<8; ++f)
      hfrag[g][f] = *(const bf16x8*)(Uin + (size_t)((kg>>1)+2*f)*cs
                                     + (size_t)(m0+g*16+lr)*16 + (kg&1)*8);
  const u16* wrow = WT + (size_t)lr*256 + kg*8;
  bf16x8 wv[8];
  #pragma unroll
  for (int f=0; f<8; ++f) wv[f] = *(const bf16x8*)(wrow + f*32);
  #pragma unroll
  for (int nn=0; nn<18; ++nn){
    bf16x8 wn[8];
    if (nn < 17){
      const u16* wr2 = wrow + (size_t)(nn+1)*16*256;
      #pragma unroll
      for (int f=0; f<8; ++f) wn[f] = *(const bf16x8*)(wr2 + f*32);
    }
    f32x4 acc[2];
    #pragma unroll
    for (int g=0; g<2; ++g){
      acc[g] = (f32x4){0.f,0.f,0.f,0.f};
      #pragma unroll
      for (int f=0; f<8; ++f) acc[g] = MFMA16(wv[f], hfrag[g][f], acc[g]);
    }
    const int col0 = nn*16 + kg*4;
    if (col0 < 32){
      float4 bs4 = *(const float4*)(xpb + col0);
      #pragma unroll
      for (int g=0; g<2; ++g){
        ushort4 uv;
        uv.x = f2bf(acc[g][0]+bs4.x); uv.y = f2bf(acc[g][1]+bs4.y);
        uv.z = f2bf(acc[g][2]+bs4.z); uv.w = f2bf(acc[g][3]+bs4.w);
        *(ushort4*)(BC + (size_t)nn*cs + (size_t)(m0+g*16+lr)*16 + kg*4) = uv;
      }
    } else {
      float4 bs4 = *(const float4*)(dtb + (col0-32));
      #pragma unroll
      for (int g=0; g<2; ++g){
        float v0=acc[g][0]+bs4.x, v1=acc[g][1]+bs4.y;
        float v2=acc[g][2]+bs4.z, v3=acc[g][3]+bs4.w;
        ushort4 uv;
        uv.x = f2bf(fmaxf(v0,0.f) + __logf(1.f + __expf(-fabsf(v0))));
        uv.y = f2bf(fmaxf(v1,0.f) + __logf(1.f + __expf(-fabsf(v1))));
        uv.z = f2bf(fmaxf(v2,0.f) + __logf(1.f + __expf(-fabsf(v2))));
        uv.w = f2bf(fmaxf(v3,0.f) + __logf(1.f + __expf(-fabsf(v3))));
        *(ushort4*)(DT + (size_t)(nn-2)*cs + (size_t)(m0+g*16+lr)*16 + kg*4) = uv;
      }
    }
    #pragma unroll
    for (int f=0; f<8; ++f) wv[f] = wn[f];
  }
}

/* depth-4 power tree: pw[i] = r^(i+1), i=0..15 */
static __device__ __forceinline__ void powtree(float r, float* pw){
  float p2=r*r, p3=p2*r, p4=p2*p2;
  float p5=p4*r, p6=p4*p2, p7=p4*p3, p8=p4*p4;
  pw[0]=r;  pw[1]=p2; pw[2]=p3; pw[3]=p4;
  pw[4]=p5; pw[5]=p6; pw[6]=p7; pw[7]=p8;
  pw[8]=p8*r;  pw[9]=p8*p2;  pw[10]=p8*p3;  pw[11]=p8*p4;
  pw[12]=p8*p5; pw[13]=p8*p6; pw[14]=p8*p7; pw[15]=p8*p8;
}

/* ---------- scan pass 1: local scan, end-state + sum(dt) ----------------- */
__global__ __launch_bounds__(256) void scan_p1(
    const u16* __restrict__ U, const u16* __restrict__ DT,
    const u16* __restrict__ BC, const float* __restrict__ Alog,
    u16* __restrict__ SGH, float* __restrict__ SDT, size_t cs){
  const int seg = blockIdx.x % NSEG;
  const int b   = blockIdx.x / NSEG;
  const int c   = threadIdx.x;
  const size_t coff = (size_t)(c>>4)*cs + (c&15);
  float a2[16]; bool geo = true;
  #pragma unroll
  for (int i=0;i<16;++i){
    float A = -__expf(Alog[c*16+i]);
    a2[i] = A * 1.44269504f;
    if (fabsf(A + (float)(i+1)) > 1e-3f) geo = false;
  }
  float h[16];
  #pragma unroll
  for (int i=0;i<16;++i) h[i]=0.f;
  float sdt = 0.f;
  const size_t mbase = (size_t)b*SEQ + (size_t)seg*LSEG;
  if (geo){
    for (int t=0;t<LSEG;++t){
      const size_t m = mbase + t;
      float u  = bf2f(U [coff + m*16]);
      float dt = bf2f(DT[coff + m*16]);
      bf16x8 b0 = *(const bf16x8*)(BC + m*16);
      bf16x8 b1 = *(const bf16x8*)(BC + m*16 + 8);
      float du = dt*u; sdt += dt;
      float r = exp2f(-1.44269504f*dt);
      float pw[16]; powtree(r, pw);
      #pragma unroll
      for (int i=0;i<8;++i)  h[i]   = h[i]  *pw[i]   + du*bf2f((u16)b0[i]);
      #pragma unroll
      for (int i=8;i<16;++i) h[i]   = h[i]  *pw[i]   + du*bf2f((u16)b1[i-8]);
    }
  } else {
    for (int t=0;t<LSEG;++t){
      const size_t m = mbase + t;
      float u  = bf2f(U [coff + m*16]);
      float dt = bf2f(DT[coff + m*16]);
      bf16x8 b0 = *(const bf16x8*)(BC + m*16);
      bf16x8 b1 = *(const bf16x8*)(BC + m*16 + 8);
      float du = dt*u; sdt += dt;
      #pragma unroll
      for (int i=0;i<16;++i){
        float Bv = (i<8) ? bf2f((u16)b0[i]) : bf2f((u16)b1[i-8]);
        h[i] = h[i]*exp2f(dt*a2[i]) + du*Bv;
      }
    }
  }
  const size_t kb = ((size_t)b*NSEG+seg);
  #pragma unroll
  for (int i=0;i<16;++i) SGH[(kb*16+i)*256 + c] = f2bf(h[i]);
  SDT[kb*256 + c] = sdt;
}

/* ---------- scan pass 2: combine; SGH <- h0 per segment ------------------ */
__global__ __launch_bounds__(256) void scan_p2(
    u16* __restrict__ SGH, const float* __restrict__ SDT,
    const float* __restrict__ Alog){
  const int i = blockIdx.x & 15, b = blockIdx.x >> 4, c = threadIdx.x;
  const float a2 = -__expf(Alog[c*16+i]) * 1.44269504f;
  float h = 0.f;
  for (int s=0;s<NSEG;++s){
    const size_t kb = ((size_t)b*NSEG+s);
    float sdt = SDT[kb*256 + c];
    size_t k = (kb*16+i)*256 + c;
    float hl = bf2f(SGH[k]);
    SGH[k] = f2bf(h);
    h = h*exp2f(sdt*a2) + hl;
  }
}

/* ---------- scan pass 3: re-scan from h0, ys in place of U (tiled) ------- */
__global__ __launch_bounds__(256) void scan_p3(
    u16* __restrict__ UY, const u16* __restrict__ DT, const u16* __restrict__ BC,
    const u16* __restrict__ ZS, const float* __restrict__ Alog,
    const float* __restrict__ Dp, const u16* __restrict__ SGH, size_t cs){
  const int seg = blockIdx.x % NSEG;
  const int b   = blockIdx.x / NSEG;
  const int c   = threadIdx.x;
  const size_t coff = (size_t)(c>>4)*cs + (c&15);
  float a2[16]; bool geo = true;
  #pragma unroll
  for (int i=0;i<16;++i){
    float A = -__expf(Alog[c*16+i]);
    a2[i] = A * 1.44269504f;
    if (fabsf(A + (float)(i+1)) > 1e-3f) geo = false;
  }
  const float Dv = Dp[c];
  const size_t kb = ((size_t)b*NSEG+seg);
  float h[16];
  #pragma unroll
  for (int i=0;i<16;++i) h[i] = bf2f(SGH[(kb*16+i)*256 + c]);
  const size_t mbase = (size_t)b*SEQ + (size_t)seg*LSEG;
  if (geo){
    for (int t=0;t<LSEG;++t){
      const size_t m = mbase + t;
      float u  = bf2f(UY[coff + m*16]);
      float dt = bf2f(DT[coff + m*16]);
      float zs = bf2f(ZS[coff + m*16]);
      bf16x8 b0 = *(const bf16x8*)(BC + m*16);
      bf16x8 b1 = *(const bf16x8*)(BC + m*16 + 8);
      bf16x8 c0 = *(const bf16x8*)(BC + cs + m*16);
      bf16x8 c1 = *(const bf16x8*)(BC + cs + m*16 + 8);
      float du = dt*u;
      float r = exp2f(-1.44269504f*dt);
      float pw[16]; powtree(r, pw);
      float s0=0.f, s1=0.f;
      #pragma unroll
      for (int i=0;i<8;++i){
        h[i] = h[i]*pw[i] + du*bf2f((u16)b0[i]);
        s0 += h[i]*bf2f((u16)c0[i]);
      }
      #pragma unroll
      for (int i=8;i<16;++i){
        h[i] = h[i]*pw[i] + du*bf2f((u16)b1[i-8]);
        s1 += h[i]*bf2f((u16)c1[i-8]);
      }
      float y = s0 + s1 + Dv*u;
      UY[coff + m*16] = f2bf(y*zs);
    }
  } else {
    for (int t=0;t<LSEG;++t){
      const size_t m = mbase + t;
      float u  = bf2f(UY[coff + m*16]);
      float dt = bf2f(DT[coff + m*16]);
      float zs = bf2f(ZS[coff + m*16]);
      bf16x8 b0 = *(const bf16x8*)(BC + m*16);
      bf16x8 b1 = *(const bf16x8*)(BC + m*16 + 8);
      bf16x8 c0 = *(const bf16x8*)(BC + cs + m*16);
      bf16x8 c1 = *(const bf16x8*)(BC + cs + m*16 + 8);
      float du = dt*u;
      float s0=0.f, s1=0.f;
      #pragma unroll
      for (int i=0;i<8;++i){
        h[i] = h[i]*exp2f(dt*a2[i]) + du*bf2f((u16)b0[i]);
        s0 += h[i]*bf2f((u16)c0[i]);
      }
      #pragma unroll
      for (int i=8;i<16;++i){
        h[i] = h[i]*exp2f(dt*a2[i]) + du*bf2f((u16)b1[i-8]);
        s1 += h[i]*bf2f((u16)c1[i-8]);
      }
      float y = s0 + s1 + Dv*u;
      UY[coff + m*16] = f2bf(y*zs);
    }
  }
}

/* --- GEMM3 + bf16 residual + LayerNorm, R=2, prefetch, all tiled --------- */
__global__ __launch_bounds__(256) void gemm3ln_kernel(
    const u16* __restrict__ YS, const u16* __restrict__ WT,
    const float* __restrict__ ob, const float* __restrict__ g,
    const float* __restrict__ bb, u16* __restrict__ Hb, size_t cs){
  const int lane = threadIdx.x & 63, wave = threadIdx.x >> 6;
  const int m0 = blockIdx.x*128 + wave*32;
  const int lr = lane & 15, kg = lane >> 4;
  bf16x8 hfrag[2][8];
  #pragma unroll
  for (int gg=0; gg<2; ++gg)
    #pragma unroll
    for (int f=0; f<8; ++f)
      hfrag[gg][f] = *(const bf16x8*)(YS + (size_t)((kg>>1)+2*f)*cs
                                      + (size_t)(m0+gg*16+lr)*16 + (kg&1)*8);
  const u16* wrow = WT + (size_t)lr*256 + kg*8;
  bf16x8 wv[8];
  #pragma unroll
  for (int f=0; f<8; ++f) wv[f] = *(const bf16x8*)(wrow + f*32);
  ushort4 xvp[2][8];
  float s[2] = {0.f,0.f}, q[2] = {0.f,0.f};
  #pragma unroll
  for (int n=0; n<8; ++n){
    bf16x8 wn[8];
    if (n < 7){
      const u16* wr2 = wrow + (size_t)(n+1)*16*256;
      #pragma unroll
      for (int f=0; f<8; ++f) wn[f] = *(const bf16x8*)(wr2 + f*32);
    }
    float4 bs4 = *(const float4*)(ob + n*16 + kg*4);
    #pragma unroll
    for (int gg=0; gg<2; ++gg){
      f32x4 acc = {0.f,0.f,0.f,0.f};
      #pragma unroll
      for (int f=0; f<8; ++f) acc = MFMA16(wv[f], hfrag[gg][f], acc);
      const size_t m = (size_t)(m0 + gg*16 + lr);
      ushort4 rs = *(const ushort4*)(Hb + (size_t)n*cs + m*16 + kg*4);
      float x0 = acc[0] + bs4.x + bf2f(rs.x);
      float x1 = acc[1] + bs4.y + bf2f(rs.y);
      float x2 = acc[2] + bs4.z + bf2f(rs.z);
      float x3 = acc[3] + bs4.w + bf2f(rs.w);
      s[gg] += (x0+x1)+(x2+x3);
      q[gg] += (x0*x0+x1*x1)+(x2*x2+x3*x3);
      ushort4 pv; pv.x=f2bf(x0); pv.y=f2bf(x1); pv.z=f2bf(x2); pv.w=f2bf(x3);
      xvp[gg][n] = pv;
    }
    #pragma unroll
    for (int f=0; f<8; ++f) wv[f] = wn[f];
  }
  #pragma unroll
  for (int gg=0; gg<2; ++gg){
    float ss = s[gg], qq = q[gg];
    ss += __shfl_xor(ss,16); qq += __shfl_xor(qq,16);
    ss += __shfl_xor(ss,32); qq += __shfl_xor(qq,32);
    float mu  = ss * 0.0078125f;
    float var = qq * 0.0078125f - mu*mu;
    float inv = rsqrtf(var + 1e-5f);
    const size_t m = (size_t)(m0 + gg*16 + lr);
    #pragma unroll
    for (int n=0;n<8;++n){
      float4 g4 = *(const float4*)(g  + n*16 + kg*4);
      float4 b4 = *(const float4*)(bb + n*16 + kg*4);
      ushort4 pv = xvp[gg][n];
      ushort4 uv;
      uv.x = f2bf((bf2f(pv.x)-mu)*inv*g4.x + b4.x);
      uv.y = f2bf((bf2f(pv.y)-mu)*inv*g4.y + b4.y);
      uv.z = f2bf((bf2f(pv.z)-mu)*inv*g4.z + b4.z);
      uv.w = f2bf((bf2f(pv.w)-mu)*inv*g4.w + b4.w);
      *(ushort4*)(Hb + (size_t)n*cs + m*16 + kg*4) = uv;
    }
  }
}

/* ---------------- two-stage mean over SEQ (tiled bf16 Hb) ---------------- */
__global__ __launch_bounds__(128) void pool1_kernel(
    const u16* __restrict__ Hb, float* __restrict__ PP, size_t cs){
  const int blk = blockIdx.x;
  const int tc = blk & 15, b = blk >> 4;
  const int d = threadIdx.x;
  const size_t coff = (size_t)(d>>4)*cs + (d&15);
  float s = 0.f;
  const size_t base = ((size_t)b*SEQ + tc*128);
  for (int t=0;t<128;++t) s += bf2f(Hb[coff + (base+t)*16]);
  PP[((size_t)b*16 + tc)*128 + d] = s;
}
__global__ __launch_bounds__(128) void pool2_kernel(
    const float* __restrict__ PP, float* __restrict__ P){
  const int b = blockIdx.x, d = threadIdx.x;
  float s = 0.f;
  #pragma unroll
  for (int tc=0;tc<16;++tc) s += PP[((size_t)b*16+tc)*128 + d];
  P[b*128 + d] = s * (1.f/SEQ);
}

/* ------------- head MLP + final formula (block per batch row) ----------- */
__global__ __launch_bounds__(64) void head_kernel(
    const float* __restrict__ P, const float* __restrict__ o1w,
    const float* __restrict__ o1b, const float* __restrict__ o2w,
    const float* __restrict__ o2b, const float* __restrict__ origins,
    float* __restrict__ out){
  const int b = blockIdx.x;
  const int j = threadIdx.x;
  float hv = o1b[j];
  #pragma unroll 4
  for (int d=0; d<128; ++d) hv += P[b*128+d]*o1w[d*64+j];
  hv = fmaxf(hv, 0.f);
  float p0 = hv*o2w[j*3+0], p1 = hv*o2w[j*3+1], p2 = hv*o2w[j*3+2];
  #pragma unroll
  for (int o=1;o<64;o<<=1){
    p0 += __shfl_xor(p0,o); p1 += __shfl_xor(p1,o); p2 += __shfl_xor(p2,o);
  }
  if (j == 0){
    float a = 2.f*sigm(p0 + o2b[0]);
    float bb = 2.f*sigm(p1 + o2b[1]);
    float c = 2.f*sigm(p2 + o2b[2]);
    const float* l1 = origins + ((size_t)b*SEQ + (SEQ-1))*16;
    const float* l2 = origins + ((size_t)b*SEQ + (SEQ-2))*16;
    float price=l1[0], ry_n=l1[1], ry_b=l2[1], gy_n=l1[2], gy_b=l2[2], ny_n=l1[3], ny_b=l2[3];
    out[b] = price*a*ry_n/ry_b*2.f*(bb*sigm(gy_n-gy_b) + c*sigm(ny_n-ny_b));
  }
}

extern "C" void kernel_launch(void* const* d_in, const int* in_sizes, int n_in,
                              void* d_out, int out_size, void* d_ws, size_t ws_size,
                              hipStream_t stream){
  const float* origins = (const float*)d_in[0];
  const float* x      = (const float*)d_in[1];
  const float* emb_w  = (const float*)d_in[2];
  const float* emb_b  = (const float*)d_in[3];
  const float* in_w   = (const float*)d_in[4];
  const float* in_b   = (const float*)d_in[5];
  const float* xp_w   = (const float*)d_in[6];
  const float* xp_b   = (const float*)d_in[7];
  const float* dt_w   = (const float*)d_in[8];
  const float* dt_b   = (const float*)d_in[9];
  const float* out_w  = (const float*)d_in[10];
  const float* out_b  = (const float*)d_in[11];
  const float* A_log  = (const float*)d_in[12];
  const float* Dp     = (const float*)d_in[13];
  const float* ln_g   = (const float*)d_in[14];
  const float* ln_b   = (const float*)d_in[15];
  const float* o1_w   = (const float*)d_in[16];
  const float* o1_b   = (const float*)d_in[17];
  const float* o2_w   = (const float*)d_in[18];
  const float* o2_b   = (const float*)d_in[19];
  float* outp = (float*)d_out;

  auto al = [](size_t b)->size_t{ return (b + 255) & ~(size_t)255; };
  const size_t wt1_b = al((size_t)NLAYERS*512*128*2);
  const size_t wt2_b = al((size_t)NLAYERS*288*256*2);
  const size_t wt3_b = al((size_t)NLAYERS*128*256*2);
  const size_t po_b  = al((size_t)B_SZ*128*4);
  const size_t pp_b  = al((size_t)B_SZ*16*128*4);
  const size_t fixed = wt1_b + wt2_b + wt3_b + po_b + pp_b;

  int CB = 0;
  static const int cbc[7] = {64,32,16,8,4,2,1};
  size_t hb_b=0, u_b=0, bc_b=0, sgh_b=0, sdt_b=0;
  for (int i=0;i<7;++i){
    int cb = cbc[i];
    size_t csz = (size_t)cb*SEQ*16;               /* chunk stride, elements */
    size_t hbb = al(8*csz*2);
    size_t uu  = al(16*csz*2);
    size_t bb  = al(2*csz*2);
    size_t sgh = al((size_t)cb*NSEG*DSTATE*DINNER*2);
    size_t sdt = al((size_t)cb*NSEG*DINNER*4);
    if (fixed + hbb + 3*uu + bb + sgh + sdt <= ws_size){
      CB=cb; hb_b=hbb; u_b=uu; bc_b=bb; sgh_b=sgh; sdt_b=sdt; break;
    }
  }
  if (!CB) return;

  char* ws = (char*)d_ws;
  size_t off = 0;
  auto take = [&](size_t bytes)->char*{ char* p = ws + off; off += bytes; return p; };
  u16*   WT1 = (u16*)take(wt1_b);
  u16*   WT2 = (u16*)take(wt2_b);
  u16*   WT3 = (u16*)take(wt3_b);
  float* PO  = (float*)take(po_b);
  float* PP  = (float*)take(pp_b);
  u16*   Hb  = (u16*)take(hb_b);
  u16*   U   = (u16*)take(u_b);
  u16*   ZS  = (u16*)take(u_b);
  u16*   DT  = (u16*)take(u_b);
  u16*   BC  = (u16*)take(bc_b);
  u16*   SGH = (u16*)take(sgh_b);
  float* SDT = (float*)take(sdt_b);

  prep_kernel<<<3360, 256, 0, stream>>>(in_w, xp_w, dt_w, out_w, WT1, WT2, WT3);

  const int NC = B_SZ / CB;
  const int Mc = CB * SEQ;
  const size_t cs = (size_t)Mc*16;
  for (int ci=0; ci<NC; ++ci){
    const int b0 = ci * CB;
    const size_t R0 = (size_t)b0 * SEQ;
    emb_kernel<<<(Mc*DMODEL)/256, 256, 0, stream>>>(x + R0*16, emb_w, emb_b, Hb, cs);
    for (int l=0;l<NLAYERS;++l){
      const float* Al = A_log + (size_t)l*DINNER*DSTATE;
      gemm1_kernel<<<(Mc/256)*2, 256, 0, stream>>>(Hb, WT1 + (size_t)l*512*128,
                                                   in_b + l*512, U, ZS, cs);
      gemm2_kernel<<<Mc/128, 256, 0, stream>>>(U, WT2 + (size_t)l*288*256,
                                               xp_b + l*32, dt_b + l*256, BC, DT, cs);
      scan_p1<<<CB*NSEG, 256, 0, stream>>>(U, DT, BC, Al, SGH, SDT, cs);
      scan_p2<<<CB*16, 256, 0, stream>>>(SGH, SDT, Al);
      scan_p3<<<CB*NSEG, 256, 0, stream>>>(U, DT, BC, ZS, Al, Dp + l*DINNER,
                                           SGH, cs);
      gemm3ln_kernel<<<Mc/128, 256, 0, stream>>>(U, WT3 + (size_t)l*128*256,
                                                 out_b + l*128, ln_g + l*128,
                                                 ln_b + l*128, Hb, cs);
    }
    pool1_kernel<<<CB*16, 128, 0, stream>>>(Hb, PP, cs);
    pool2_kernel<<<CB, 128, 0, stream>>>(PP, PO + (size_t)b0*128);
  }
  head_kernel<<<B_SZ, 64, 0, stream>>>(PO, o1_w, o1_b, o2_w, o2_b, origins, outp);
}